// Round 8
// baseline (573.580 us; speedup 1.0000x reference)
//
#include <hip/hip_runtime.h>
#include <hip/hip_bf16.h>
#include <math.h>

#define B_    128
#define CIN   128
#define TIN   2500
#define COUT  64
#define KW    27
#define TOUT  625
#define TPAD  640   // padded t extent for bf16 q/k/v planes
#define CTT   32    // conv t-tile
#define GROWS 152   // conv staging rows (span 4*31+27=151, pad to 152)
#define SCS   644   // attn score-row stride (644*4 B = 16 mod 128 B -> spread bank starts)

typedef __bf16 bf16x8 __attribute__((ext_vector_type(8)));
typedef float  f32x4  __attribute__((ext_vector_type(4)));

// packed f32x2 -> bf16x2 (RNE, native v_cvt_pk_bf16_f32 on gfx950); a = low half
__device__ __forceinline__ unsigned cvt2_bf16(float a, float b) {
    union { __hip_bfloat162 h2; unsigned u; } r;
    r.h2 = __float22bfloat162_rn(make_float2(a, b));
    return r.u;
}

__device__ __forceinline__ unsigned short f32_to_bf16_rne(float v) {
    unsigned u = __float_as_uint(v);
    u += 0x7FFFu + ((u >> 16) & 1u);
    return (unsigned short)(u >> 16);
}

__device__ __forceinline__ f32x4 mfma_bf16(bf16x8 a, bf16x8 b, f32x4 c) {
    return __builtin_amdgcn_mfma_f32_16x16x32_bf16(a, b, c, 0, 0, 0);
}

// ---------------------------------------------------------------------------
// K0: alpha[o] = mean|w|; position-engineered packed signs:
//   word w = sgn2[(kk*4+kg)*64 + o]. For chunk cs, reg j, the A-frag u32 is
//   ((w << (4cs+j)) & 0x80008000) | 0x3F803F80:
//     bit(15-4cs-j) = sign(c = cs*32+kg*8+2j), bit(31-4cs-j) = sign(c+1),
//   sign-bit = 1 iff weight <= 0 (-> bf16 -1.0).
// ---------------------------------------------------------------------------
__global__ void binarize_kernel(const float* __restrict__ w,
                                unsigned* __restrict__ sgn2,
                                float* __restrict__ alpha_out) {
    int o = blockIdx.x, tid = threadIdx.x;
    __shared__ float red[256];
    const float* wo_ = w + (size_t)o * (CIN * KW);
    float s = 0.f;
    for (int idx = tid; idx < CIN * KW; idx += 256) s += fabsf(wo_[idx]);
    red[tid] = s;
    __syncthreads();
    for (int st = 128; st > 0; st >>= 1) {
        if (tid < st) red[tid] += red[tid + st];
        __syncthreads();
    }
    if (tid == 0) alpha_out[o] = red[0] / (float)(CIN * KW);

    for (int t = tid; t < KW * 4; t += 256) {
        int kk = t >> 2, kg = t & 3;
        unsigned v = 0;
#pragma unroll
        for (int cs = 0; cs < 4; cs++) {
#pragma unroll
            for (int j = 0; j < 4; j++) {
                int c0 = cs * 32 + kg * 8 + 2 * j;
                unsigned blo = (wo_[c0 * KW + kk] > 0.f) ? 0u : 1u;
                unsigned bhi = (wo_[(c0 + 1) * KW + kk] > 0.f) ? 0u : 1u;
                int sft = 4 * cs + j;
                v |= blo << (15 - sft);
                v |= bhi << (31 - sft);
            }
        }
        sgn2[(kk * 4 + kg) * 64 + o] = v;
    }
}

// ---------------------------------------------------------------------------
// K0b: blocks 0-2: transpose wq/wk/wv -> wT[c][o]; block 3: wo -> bf16 hi/lo
//      [o][c]; block 4: fold alpha+bias+BN into scA/scB
// ---------------------------------------------------------------------------
__global__ void transpose_w_kernel(const float* __restrict__ wq, const float* __restrict__ wk,
                                   const float* __restrict__ wv, const float* __restrict__ wo,
                                   const float* __restrict__ conv_b, const float* __restrict__ gamma_,
                                   const float* __restrict__ beta_, const float* __restrict__ mean_,
                                   const float* __restrict__ var_, const float* __restrict__ alpha_,
                                   float* __restrict__ dstT,
                                   unsigned short* __restrict__ wo_h, unsigned short* __restrict__ wo_l,
                                   float* __restrict__ scA, float* __restrict__ scB) {
    if (blockIdx.x < 3) {
        const float* srcs[3] = {wq, wk, wv};
        const float* src = srcs[blockIdx.x];
        float* dst = dstT + (size_t)blockIdx.x * 4096;
        for (int idx = threadIdx.x; idx < 4096; idx += 256) {
            int o = idx >> 6, c = idx & 63;
            dst[c * 64 + o] = src[idx];
        }
    } else if (blockIdx.x == 3) {
        for (int idx = threadIdx.x; idx < 4096; idx += 256) {
            float v = wo[idx];
            unsigned short h = f32_to_bf16_rne(v);
            float hf = __uint_as_float((unsigned)h << 16);
            wo_h[idx] = h;
            wo_l[idx] = f32_to_bf16_rne(v - hf);
        }
    } else {
        int o = threadIdx.x;
        if (o < 64) {
            float inv = rsqrtf(var_[o] + 1e-5f);
            float G = gamma_[o] * inv;
            scA[o] = alpha_[o] * G;
            scB[o] = (conv_b[o] - mean_[o]) * G + beta_[o];
        }
    }
}

// ---------------------------------------------------------------------------
// K1: binarized conv1d via bf16 MFMA (hi-plane only) + BN/ELU -> y.
//   Wave w: o in [16w,16w+16), all 32 t. A-frags built from packed signs with
//   2 inst/u32 (shl + and_or). LDS = x hi plane (38.9 KB) -> 4 blocks/CU.
// ---------------------------------------------------------------------------
__global__ __launch_bounds__(256, 4) void conv_kernel(
    const float* __restrict__ x, const unsigned* __restrict__ sgn2,
    const float* __restrict__ scA, const float* __restrict__ scB,
    float* __restrict__ y_out)
{
    __shared__ __align__(16) unsigned short xhi[GROWS * 128];  // 38912 B

    int b = blockIdx.y;
    int t0 = blockIdx.x * CTT;
    int tid = threadIdx.x;

    // ---- stage x (hi bf16, RNE packed cvt): task = (c8, gl) -> one b128 ----
    const float* xb = x + (size_t)b * CIN * TIN;
    int gbase = 4 * t0 - 13;
    for (int task = tid; task < 16 * GROWS; task += 256) {
        int c8 = task / GROWS, gl = task - c8 * GROWS;
        int g = gbase + gl;
        bool valid = (gl < 151) && ((unsigned)g < (unsigned)TIN);
        float vs[8];
#pragma unroll
        for (int j = 0; j < 8; j++)
            vs[j] = valid ? xb[(size_t)(c8 * 8 + j) * TIN + g] : 0.f;
        union { unsigned u[4]; uint4 q; } H;
#pragma unroll
        for (int j = 0; j < 4; j++)
            H.u[j] = cvt2_bf16(vs[2 * j], vs[2 * j + 1]);
        int c8p = c8 ^ ((gl >> 2) & 15);
        *(uint4*)(xhi + gl * 128 + c8p * 8) = H.q;
    }
    __syncthreads();

    // ---- MFMA K-loop ----
    int wave = tid >> 6, lane = tid & 63;
    int o0 = wave * 16;             // 16-o slice per wave
    int n = lane & 15, kg = lane >> 4;

    f32x4 acc0 = {0.f, 0.f, 0.f, 0.f};   // t-tile 0 (t0..t0+15)
    f32x4 acc1 = {0.f, 0.f, 0.f, 0.f};   // t-tile 1 (t0+16..t0+31)

    const unsigned* sgb = sgn2 + (size_t)kg * 64 + o0 + n;
    unsigned sa = sgb[0];

#pragma unroll 1
    for (int kk = 0; kk < KW; ++kk) {
        unsigned na = 0;
        if (kk < KW - 1) na = sgb[(kk + 1) * 256];   // prefetch (L1-hot)
        int gl = 4 * n + kk;                          // t-tile 0 row
        int rot = (gl >> 2) & 15;                     // same rot for gl+64
        const unsigned short* xr0 = xhi + gl * 128;
        const unsigned short* xr1 = xr0 + 8192;       // +64 rows
#pragma unroll
        for (int cs = 0; cs < 4; ++cs) {
            int c8p = (cs * 4 + kg) ^ rot;
            bf16x8 b0 = *(const bf16x8*)(xr0 + c8p * 8);
            bf16x8 b1 = *(const bf16x8*)(xr1 + c8p * 8);
            unsigned sh = sa << (4 * cs);
            union { unsigned u[4]; bf16x8 v; } A;
            A.u[0] = (sh & 0x80008000u) | 0x3F803F80u;
            A.u[1] = ((sh << 1) & 0x80008000u) | 0x3F803F80u;
            A.u[2] = ((sh << 2) & 0x80008000u) | 0x3F803F80u;
            A.u[3] = ((sh << 3) & 0x80008000u) | 0x3F803F80u;
            acc0 = mfma_bf16(A.v, b0, acc0);
            acc1 = mfma_bf16(A.v, b1, acc1);
        }
        sa = na;
    }

    // ---- epilogue: C col = lane&15 (t), row = quad*4+r (o-within-16) ----
    int quad = lane >> 4, col = lane & 15;
#pragma unroll
    for (int tt = 0; tt < 2; ++tt) {
        int t_g = t0 + tt * 16 + col;
        if (t_g < TOUT) {
            f32x4 a = tt ? acc1 : acc0;
#pragma unroll
            for (int r = 0; r < 4; ++r) {
                int o = o0 + quad * 4 + r;
                float s = a[r] * scA[o] + scB[o];
                float yv = s > 0.f ? s : (__expf(s) - 1.0f);
                y_out[((size_t)b * COUT + o) * TOUT + t_g] = yv;
            }
        }
    }
}

// ---------------------------------------------------------------------------
// K1b: projections q=wq@spike(y), k=wk@spike(y), v=wv@y as tiled GEMM.
//   Outputs bf16: q_h,k_h [b][t(640)][c]; vT_h [b][c][t(640)]. Pad t>=625 -> 0.
// ---------------------------------------------------------------------------
__global__ __launch_bounds__(256, 2) void proj_kernel(
    const float* __restrict__ y, const float* __restrict__ wqT,
    const float* __restrict__ wkT, const float* __restrict__ wvT,
    unsigned short* __restrict__ q_h, unsigned short* __restrict__ k_h,
    unsigned short* __restrict__ vT_h)
{
    __shared__ float y_sh[64 * 132];   // stride 132, 33792 B
    int b = blockIdx.y, t0 = blockIdx.x * 128, tid = threadIdx.x;

    const float* yb = y + (size_t)b * COUT * TOUT;
    for (int i = tid; i < 64 * 128; i += 256) {
        int c = i >> 7, tt = i & 127;
        int t = t0 + tt;
        y_sh[c * 132 + tt] = (t < TOUT) ? yb[c * TOUT + t] : 0.f;
    }
    __syncthreads();

    int oo = tid & 63, tq = tid >> 6;
    float q[32], k[32], v[32];
#pragma unroll
    for (int j = 0; j < 32; j++) { q[j] = 0.f; k[j] = 0.f; v[j] = 0.f; }

#pragma unroll 1
    for (int c = 0; c < 64; ++c) {
        float wq = wqT[c * 64 + oo];
        float wk = wkT[c * 64 + oo];
        float wv = wvT[c * 64 + oo];
        const float* yr = &y_sh[c * 132 + tq * 32];
#pragma unroll
        for (int j = 0; j < 32; ++j) {
            float yv = yr[j];
            float sp = yv > 0.f ? 1.f : 0.f;
            q[j] += wq * sp; k[j] += wk * sp; v[j] += wv * yv;
        }
    }

    int tbase = t0 + tq * 32;
#pragma unroll
    for (int j = 0; j < 32; ++j) {
        size_t off = ((size_t)b * TPAD + tbase + j) * 64 + oo;
        q_h[off] = f32_to_bf16_rne(q[j]);
        k_h[off] = f32_to_bf16_rne(k[j]);
    }
    union { unsigned u[16]; uint4 q4[4]; } V;
#pragma unroll
    for (int j = 0; j < 16; ++j) V.u[j] = cvt2_bf16(v[2 * j], v[2 * j + 1]);
    unsigned short* vp = vT_h + ((size_t)b * 64 + oo) * TPAD + tbase;
#pragma unroll
    for (int i = 0; i < 4; i++) ((uint4*)vp)[i] = V.q4[i];
}

// ---------------------------------------------------------------------------
// K2: MFMA attention per (b, 16-t tile).
// ---------------------------------------------------------------------------
__global__ __launch_bounds__(256, 3) void attn_kernel(
    const unsigned short* __restrict__ q_h, const unsigned short* __restrict__ k_h,
    const unsigned short* __restrict__ vT_h, const float* __restrict__ y,
    const unsigned short* __restrict__ wo_h, const unsigned short* __restrict__ wo_l,
    float* __restrict__ out)
{
    __shared__ float sc_sh[16 * SCS];   // 41216 B, stride 644
    __shared__ float ctx_sh[64 * 17];   // 4352 B
    __shared__ float red_sh[256];
    __shared__ float rden[16];

    int b = blockIdx.y, t0 = blockIdx.x * 16, tid = threadIdx.x;
    int wave = tid >> 6, lane = tid & 63;
    int quad = lane >> 4, nlo = lane & 15;

    // ---- scores: wave w covers s in [w*160, (w+1)*160) ----
    const unsigned short* qb = q_h + ((size_t)b * TPAD + t0 + nlo) * 64 + quad * 8;
    bf16x8 qa0 = *(const bf16x8*)(qb);
    bf16x8 qa1 = *(const bf16x8*)(qb + 32);
    const unsigned short* kbase = k_h + (size_t)b * TPAD * 64 + quad * 8;
#pragma unroll 5
    for (int nt = 0; nt < 10; ++nt) {
        int s = (wave * 10 + nt) * 16 + nlo;
        const unsigned short* krow = kbase + (size_t)s * 64;
        bf16x8 kb0 = *(const bf16x8*)(krow);
        bf16x8 kb1 = *(const bf16x8*)(krow + 32);
        f32x4 acc = {0.f, 0.f, 0.f, 0.f};
        acc = mfma_bf16(qa0, kb0, acc);
        acc = mfma_bf16(qa1, kb1, acc);
#pragma unroll
        for (int r = 0; r < 4; ++r)
            sc_sh[(quad * 4 + r) * SCS + s] = acc[r] * 0.125f;
    }
    __syncthreads();

    // ---- softmax over s (2-pass) ----
    int ti1 = tid >> 4, sg = tid & 15;
    float mx = -3.0e38f;
    for (int s = sg; s < TOUT; s += 16) mx = fmaxf(mx, sc_sh[ti1 * SCS + s]);
    red_sh[tid] = mx;
    __syncthreads();
    float rowm = red_sh[ti1 * 16];
#pragma unroll
    for (int l = 1; l < 16; l++) rowm = fmaxf(rowm, red_sh[ti1 * 16 + l]);
    __syncthreads();
    float sum = 0.f;
    for (int s = sg; s < TOUT; s += 16) {
        float e = __expf(sc_sh[ti1 * SCS + s] - rowm);
        sc_sh[ti1 * SCS + s] = e;
        sum += e;
    }
    red_sh[tid] = sum;
    __syncthreads();
    if (tid < 16) {
        float tot = 0.f;
#pragma unroll
        for (int l = 0; l < 16; l++) tot += red_sh[tid * 16 + l];
        rden[tid] = 1.f / tot;
    }
    __syncthreads();

    // ---- PV: wave w -> c-tile w. K = s, 20 steps of 32 ----
    const unsigned short* vb = vT_h + ((size_t)b * 64 + wave * 16 + nlo) * TPAD;
    f32x4 cacc = {0.f, 0.f, 0.f, 0.f};
#pragma unroll 4
    for (int ks = 0; ks < 20; ++ks) {
        const float* pr = &sc_sh[nlo * SCS + ks * 32 + quad * 8];
        union { unsigned u[4]; bf16x8 v; } P;
#pragma unroll
        for (int j = 0; j < 4; ++j) P.u[j] = cvt2_bf16(pr[2 * j], pr[2 * j + 1]);
        bf16x8 v8 = *(const bf16x8*)(vb + ks * 32 + quad * 8);
        cacc = mfma_bf16(P.v, v8, cacc);
    }
#pragma unroll
    for (int r = 0; r < 4; ++r)
        ctx_sh[(wave * 16 + nlo) * 17 + quad * 4 + r] = cacc[r] * rden[quad * 4 + r];
    __syncthreads();

    // ---- epilogue: out = y + wo @ ctx. Wave w -> o-tile w. ----
    const unsigned short* woh = wo_h + (size_t)(wave * 16 + nlo) * 64 + quad * 8;
    const unsigned short* wol = wo_l + (size_t)(wave * 16 + nlo) * 64 + quad * 8;
    f32x4 oacc = {0.f, 0.f, 0.f, 0.f};
#pragma unroll
    for (int ks = 0; ks < 2; ++ks) {
        union { unsigned u[4]; bf16x8 v; } Bc;
#pragma unroll
        for (int j = 0; j < 4; ++j)
            Bc.u[j] = cvt2_bf16(ctx_sh[(ks * 32 + quad * 8 + 2 * j) * 17 + nlo],
                                ctx_sh[(ks * 32 + quad * 8 + 2 * j + 1) * 17 + nlo]);
        bf16x8 ah = *(const bf16x8*)(woh + ks * 32);
        bf16x8 al = *(const bf16x8*)(wol + ks * 32);
        oacc = mfma_bf16(ah, Bc.v, oacc);
        oacc = mfma_bf16(al, Bc.v, oacc);
    }
    int t_g = t0 + nlo;
    if (t_g < TOUT) {
#pragma unroll
        for (int r = 0; r < 4; ++r) {
            int o = wave * 16 + quad * 4 + r;
            size_t off = ((size_t)b * COUT + o) * TOUT + t_g;
            out[off] = y[off] + oacc[r];
        }
    }
}

// ---------------------------------------------------------------------------
extern "C" void kernel_launch(void* const* d_in, const int* in_sizes, int n_in,
                              void* d_out, int out_size, void* d_ws, size_t ws_size,
                              hipStream_t stream) {
    const float* x        = (const float*)d_in[0];
    const float* conv_w   = (const float*)d_in[1];
    const float* conv_b   = (const float*)d_in[2];
    const float* bn_gamma = (const float*)d_in[3];
    const float* bn_beta  = (const float*)d_in[4];
    const float* bn_mean  = (const float*)d_in[5];
    const float* bn_var   = (const float*)d_in[6];
    const float* wq       = (const float*)d_in[7];
    const float* wk       = (const float*)d_in[8];
    const float* wv       = (const float*)d_in[9];
    const float* wo       = (const float*)d_in[10];
    float* out = (float*)d_out;
    float* ws  = (float*)d_ws;

    // ws layout (float offsets)
    unsigned* sgn2        = (unsigned*)ws;                    // 6912 u32
    float* alpha          = ws + 110592;                      // 64
    float* scA            = ws + 110656;                      // 64
    float* scB            = ws + 110720;                      // 64
    float* wT4            = ws + 110848;                      // 3*4096 -> 123136
    unsigned short* wo_h  = (unsigned short*)(ws + 123136);   // 2048 f
    unsigned short* wo_l  = (unsigned short*)(ws + 125184);   // 2048 f -> 127232
    float* yb             = ws + 131072;                      // 5,120,000
    unsigned short* q_h   = (unsigned short*)(ws + 5251072);  // 2,621,440 f
    unsigned short* k_h   = (unsigned short*)(ws + 7872512);  // 2,621,440 f
    unsigned short* vT_h  = (unsigned short*)(ws + 10493952); // ends 13,115,392 f

    hipLaunchKernelGGL(binarize_kernel, dim3(64), dim3(256), 0, stream, conv_w, sgn2, alpha);
    hipLaunchKernelGGL(transpose_w_kernel, dim3(5), dim3(256), 0, stream,
                       wq, wk, wv, wo, conv_b, bn_gamma, bn_beta, bn_mean, bn_var, alpha,
                       wT4, wo_h, wo_l, scA, scB);
    hipLaunchKernelGGL(conv_kernel, dim3(20, 128), dim3(256), 0, stream,
                       x, sgn2, scA, scB, yb);
    hipLaunchKernelGGL(proj_kernel, dim3(5, 128), dim3(256), 0, stream,
                       yb, wT4, wT4 + 4096, wT4 + 8192, q_h, k_h, vT_h);
    hipLaunchKernelGGL(attn_kernel, dim3(40, 128), dim3(256), 0, stream,
                       q_h, k_h, vT_h, yb, wo_h, wo_l, out);
}

// Round 9
// 494.667 us; speedup vs baseline: 1.1595x; 1.1595x over previous
//
#include <hip/hip_runtime.h>
#include <math.h>

#define B_    128
#define CIN   128
#define TIN   2500
#define COUT  64
#define KW    27
#define TOUT  625
#define TPAD  640   // padded t extent for bf16 q/k/v planes
#define CTT   32    // conv t-tile
#define GROWS 152   // conv staging rows (span 4*31+27=151, pad to 152)

typedef __bf16 bf16x8 __attribute__((ext_vector_type(8)));
typedef float  f32x4  __attribute__((ext_vector_type(4)));

__device__ __forceinline__ unsigned short f32_to_bf16_rne(float v) {
    unsigned u = __float_as_uint(v);
    u += 0x7FFFu + ((u >> 16) & 1u);
    return (unsigned short)(u >> 16);
}

__device__ __forceinline__ f32x4 mfma_bf16(bf16x8 a, bf16x8 b, f32x4 c) {
    return __builtin_amdgcn_mfma_f32_16x16x32_bf16(a, b, c, 0, 0, 0);
}

// expand 8 sign bits (bit=1 => -1.0, bit=0 => +1.0) into bf16x8 of +-1.0
__device__ __forceinline__ bf16x8 expand_sgn(unsigned b) {
    union { unsigned u[4]; bf16x8 v; } r;
#pragma unroll
    for (int j = 0; j < 4; j++) {
        unsigned lo = (b >> (2 * j)) & 1u;
        unsigned hi = (b >> (2 * j + 1)) & 1u;
        r.u[j] = 0x3F803F80u | (lo << 15) | (hi << 31);
    }
    return r.v;
}

// ---------------------------------------------------------------------------
// K0: alpha[o] = mean|w|; packed sign bits:
//     sgn2[(kk*4+kg)*64 + o] = u32, byte cs holds bits j for c = cs*32+kg*8+j
// ---------------------------------------------------------------------------
__global__ void binarize_kernel(const float* __restrict__ w,
                                unsigned* __restrict__ sgn2,
                                float* __restrict__ alpha_out) {
    int o = blockIdx.x, tid = threadIdx.x;
    __shared__ float red[256];
    const float* wo_ = w + (size_t)o * (CIN * KW);
    float s = 0.f;
    for (int idx = tid; idx < CIN * KW; idx += 256) s += fabsf(wo_[idx]);
    red[tid] = s;
    __syncthreads();
    for (int st = 128; st > 0; st >>= 1) {
        if (tid < st) red[tid] += red[tid + st];
        __syncthreads();
    }
    if (tid == 0) alpha_out[o] = red[0] / (float)(CIN * KW);

    for (int t = tid; t < KW * 4; t += 256) {
        int kk = t >> 2, kg = t & 3;
        unsigned u = 0;
#pragma unroll
        for (int cs = 0; cs < 4; cs++) {
#pragma unroll
            for (int j = 0; j < 8; j++) {
                int c = cs * 32 + kg * 8 + j;
                float v = wo_[c * KW + kk];
                unsigned bit = (v > 0.f) ? 0u : 1u;
                u |= bit << (cs * 8 + j);
            }
        }
        sgn2[(kk * 4 + kg) * 64 + o] = u;
    }
}

// ---------------------------------------------------------------------------
// K0b: blocks 0-2: transpose wq/wk/wv -> wT[c][o]; block 3: wo -> bf16 hi/lo
//      [o][c]; block 4: fold alpha+bias+BN into scA/scB
// ---------------------------------------------------------------------------
__global__ void transpose_w_kernel(const float* __restrict__ wq, const float* __restrict__ wk,
                                   const float* __restrict__ wv, const float* __restrict__ wo,
                                   const float* __restrict__ conv_b, const float* __restrict__ gamma_,
                                   const float* __restrict__ beta_, const float* __restrict__ mean_,
                                   const float* __restrict__ var_, const float* __restrict__ alpha_,
                                   float* __restrict__ dstT,
                                   unsigned short* __restrict__ wo_h, unsigned short* __restrict__ wo_l,
                                   float* __restrict__ scA, float* __restrict__ scB) {
    if (blockIdx.x < 3) {
        const float* srcs[3] = {wq, wk, wv};
        const float* src = srcs[blockIdx.x];
        float* dst = dstT + (size_t)blockIdx.x * 4096;
        for (int idx = threadIdx.x; idx < 4096; idx += 256) {
            int o = idx >> 6, c = idx & 63;
            dst[c * 64 + o] = src[idx];
        }
    } else if (blockIdx.x == 3) {
        for (int idx = threadIdx.x; idx < 4096; idx += 256) {
            float v = wo[idx];
            unsigned short h = f32_to_bf16_rne(v);
            float hf = __uint_as_float((unsigned)h << 16);
            wo_h[idx] = h;
            wo_l[idx] = f32_to_bf16_rne(v - hf);
        }
    } else {
        int o = threadIdx.x;
        if (o < 64) {
            float inv = rsqrtf(var_[o] + 1e-5f);
            float G = gamma_[o] * inv;
            scA[o] = alpha_[o] * G;
            scB[o] = (conv_b[o] - mean_[o]) * G + beta_[o];
        }
    }
}

// ---------------------------------------------------------------------------
// K1: binarized conv1d via bf16 MFMA (hi-plane only) + BN/ELU -> y.
//   R7-proven version (129 us): wave w = o slice [16w,16w+16) x 32 t,
//   packed-sign expansion in-register, 38.9 KB LDS -> 4 blocks/CU.
// ---------------------------------------------------------------------------
__global__ __launch_bounds__(256, 4) void conv_kernel(
    const float* __restrict__ x, const unsigned* __restrict__ sgn2,
    const float* __restrict__ scA, const float* __restrict__ scB,
    float* __restrict__ y_out)
{
    __shared__ __align__(16) unsigned short xhi[GROWS * 128];  // 38912 B

    int b = blockIdx.y;
    int t0 = blockIdx.x * CTT;
    int tid = threadIdx.x;

    // ---- stage x (hi bf16, RNE): task = (c8, gl); 8 loads -> one b128 ----
    const float* xb = x + (size_t)b * CIN * TIN;
    int gbase = 4 * t0 - 13;
    for (int task = tid; task < 16 * GROWS; task += 256) {
        int c8 = task / GROWS, gl = task - c8 * GROWS;
        int g = gbase + gl;
        bool valid = (gl < 151) && ((unsigned)g < (unsigned)TIN);
        float vs[8];
#pragma unroll
        for (int j = 0; j < 8; j++)
            vs[j] = valid ? xb[(size_t)(c8 * 8 + j) * TIN + g] : 0.f;
        union { unsigned u[4]; uint4 q; } H;
#pragma unroll
        for (int j = 0; j < 4; j++) {
            unsigned short h0 = f32_to_bf16_rne(vs[2 * j]);
            unsigned short h1 = f32_to_bf16_rne(vs[2 * j + 1]);
            H.u[j] = (unsigned)h0 | ((unsigned)h1 << 16);
        }
        int c8p = c8 ^ ((gl >> 2) & 15);
        *(uint4*)(xhi + gl * 128 + c8p * 8) = H.q;
    }
    __syncthreads();

    // ---- MFMA K-loop ----
    int wave = tid >> 6, lane = tid & 63;
    int o0 = wave * 16;             // 16-o slice per wave
    int n = lane & 15, kg = lane >> 4;

    f32x4 acc0 = {0.f, 0.f, 0.f, 0.f};   // t-tile 0 (t0..t0+15)
    f32x4 acc1 = {0.f, 0.f, 0.f, 0.f};   // t-tile 1 (t0+16..t0+31)

    const unsigned* sgb = sgn2 + (size_t)kg * 64 + o0 + n;
    unsigned sa = sgb[0];

#pragma unroll 1
    for (int kk = 0; kk < KW; ++kk) {
        unsigned na = 0;
        if (kk < KW - 1) na = sgb[(kk + 1) * 256];   // prefetch (L1-hot)
        int gl = 4 * n + kk;                          // t-tile 0 row
        int rot = (gl >> 2) & 15;                     // same rot for gl+64
        const unsigned short* xr0 = xhi + gl * 128;
        const unsigned short* xr1 = xr0 + 8192;       // +64 rows
#pragma unroll
        for (int cs = 0; cs < 4; ++cs) {
            int c8p = (cs * 4 + kg) ^ rot;
            bf16x8 b0 = *(const bf16x8*)(xr0 + c8p * 8);
            bf16x8 b1 = *(const bf16x8*)(xr1 + c8p * 8);
            bf16x8 a = expand_sgn((sa >> (8 * cs)) & 0xFFu);
            acc0 = mfma_bf16(a, b0, acc0);
            acc1 = mfma_bf16(a, b1, acc1);
        }
        sa = na;
    }

    // ---- epilogue: C col = lane&15 (t), row = quad*4+r (o-within-16) ----
    int quad = lane >> 4, col = lane & 15;
#pragma unroll
    for (int tt = 0; tt < 2; ++tt) {
        int t_g = t0 + tt * 16 + col;
        if (t_g < TOUT) {
            f32x4 a = tt ? acc1 : acc0;
#pragma unroll
            for (int r = 0; r < 4; ++r) {
                int o = o0 + quad * 4 + r;
                float s = a[r] * scA[o] + scB[o];
                float yv = s > 0.f ? s : expm1f(s);
                y_out[((size_t)b * COUT + o) * TOUT + t_g] = yv;
            }
        }
    }
}

// ---------------------------------------------------------------------------
// K1b: projections q=wq@spike(y), k=wk@spike(y), v=wv@y.
//   v2: ALL weights staged in LDS (48 KB) + 64-t y tile (18.4 KB): the inner
//   loop is pure LDS (broadcast y via float4, stride-1 w) -> no per-thread
//   global loads (R4/R5 pathology). Thread (oo, tq): 16 t each.
// ---------------------------------------------------------------------------
__global__ __launch_bounds__(256, 2) void proj_kernel(
    const float* __restrict__ y, const float* __restrict__ wqT,
    const float* __restrict__ wkT, const float* __restrict__ wvT,
    unsigned short* __restrict__ q_h, unsigned short* __restrict__ k_h,
    unsigned short* __restrict__ vT_h)
{
    __shared__ float w_sh[3 * 4096];          // 49152 B: wqT | wkT | wvT ([c][o])
    __shared__ __align__(16) float y_sh[64 * 72];  // 18432 B, stride 72
    int b = blockIdx.y, t0 = blockIdx.x * 64, tid = threadIdx.x;

    for (int i = tid; i < 4096; i += 256) {
        w_sh[i]         = wqT[i];
        w_sh[4096 + i]  = wkT[i];
        w_sh[8192 + i]  = wvT[i];
    }
    const float* yb = y + (size_t)b * COUT * TOUT;
    for (int i = tid; i < 64 * 64; i += 256) {
        int c = i >> 6, tt = i & 63;
        int t = t0 + tt;
        y_sh[c * 72 + tt] = (t < TOUT) ? yb[c * TOUT + t] : 0.f;
    }
    __syncthreads();

    int oo = tid & 63, tq = tid >> 6;   // tq in 0..3 -> 16 t each
    float q[16], k[16], v[16];
#pragma unroll
    for (int j = 0; j < 16; j++) { q[j] = 0.f; k[j] = 0.f; v[j] = 0.f; }

#pragma unroll 1
    for (int c = 0; c < 64; ++c) {
        float wq = w_sh[c * 64 + oo];
        float wk = w_sh[4096 + c * 64 + oo];
        float wv = w_sh[8192 + c * 64 + oo];
        const float* yr = &y_sh[c * 72 + tq * 16];
#pragma unroll
        for (int j4 = 0; j4 < 4; ++j4) {
            float4 y4 = *(const float4*)(yr + 4 * j4);
            float ys[4] = {y4.x, y4.y, y4.z, y4.w};
#pragma unroll
            for (int j = 0; j < 4; ++j) {
                float yv = ys[j];
                float sp = yv > 0.f ? 1.f : 0.f;
                q[4 * j4 + j] += wq * sp;
                k[4 * j4 + j] += wk * sp;
                v[4 * j4 + j] += wv * yv;
            }
        }
    }

    int tbase = t0 + tq * 16;
#pragma unroll
    for (int j = 0; j < 16; ++j) {
        size_t off = ((size_t)b * TPAD + tbase + j) * 64 + oo;
        q_h[off] = f32_to_bf16_rne(q[j]);
        k_h[off] = f32_to_bf16_rne(k[j]);
    }
    union { unsigned short u[16]; uint4 q4[2]; } V;
#pragma unroll
    for (int j = 0; j < 16; ++j) V.u[j] = f32_to_bf16_rne(v[j]);
    unsigned short* vp = vT_h + ((size_t)b * 64 + oo) * TPAD + tbase;
    ((uint4*)vp)[0] = V.q4[0];
    ((uint4*)vp)[1] = V.q4[1];
}

// ---------------------------------------------------------------------------
// K2: MFMA attention per (b, 16-t tile), 512 threads / 8 waves:
//   scores s-split 8 ways; softmax 32 lanes/row; PV split (c-tile x K-half)
//   with fp32 partial reconciliation in LDS; epilogue on waves 0-3.
// ---------------------------------------------------------------------------
__global__ __launch_bounds__(512, 3) void attn_kernel(
    const unsigned short* __restrict__ q_h, const unsigned short* __restrict__ k_h,
    const unsigned short* __restrict__ vT_h, const float* __restrict__ y,
    const unsigned short* __restrict__ wo_h, const unsigned short* __restrict__ wo_l,
    float* __restrict__ out)
{
    __shared__ float sc_sh[16 * 648];      // 41472 B
    __shared__ float ctx_sh[2 * 64 * 17];  // 8704 B (kh partials)
    __shared__ float red_sh[512];          // 2048 B
    __shared__ float rden[16];             // 64 B  => 52288 total -> 3 blk/CU

    int b = blockIdx.y, t0 = blockIdx.x * 16, tid = threadIdx.x;
    int wave = tid >> 6, lane = tid & 63;
    int quad = lane >> 4, nlo = lane & 15;

    // ---- scores: wave w covers s in [w*80, (w+1)*80), 5 nt steps ----
    const unsigned short* qb = q_h + ((size_t)b * TPAD + t0 + nlo) * 64 + quad * 8;
    bf16x8 qa0 = *(const bf16x8*)(qb);
    bf16x8 qa1 = *(const bf16x8*)(qb + 32);
    const unsigned short* kbase = k_h + (size_t)b * TPAD * 64 + quad * 8;
#pragma unroll 5
    for (int nt = 0; nt < 5; ++nt) {
        int s = wave * 80 + nt * 16 + nlo;
        const unsigned short* krow = kbase + (size_t)s * 64;
        bf16x8 kb0 = *(const bf16x8*)(krow);
        bf16x8 kb1 = *(const bf16x8*)(krow + 32);
        f32x4 acc = {0.f, 0.f, 0.f, 0.f};
        acc = mfma_bf16(qa0, kb0, acc);
        acc = mfma_bf16(qa1, kb1, acc);
#pragma unroll
        for (int r = 0; r < 4; ++r)
            sc_sh[(quad * 4 + r) * 648 + s] = acc[r] * 0.125f;
    }
    __syncthreads();

    // ---- softmax over s (2-pass, 32 lanes per row) ----
    int ti1 = tid >> 5, sg = tid & 31;
    float mx = -3.0e38f;
    for (int s = sg; s < TOUT; s += 32) mx = fmaxf(mx, sc_sh[ti1 * 648 + s]);
    red_sh[tid] = mx;
    __syncthreads();
    float rowm = red_sh[ti1 * 32];
#pragma unroll
    for (int l = 1; l < 32; l++) rowm = fmaxf(rowm, red_sh[ti1 * 32 + l]);
    __syncthreads();
    float sum = 0.f;
    for (int s = sg; s < TOUT; s += 32) {
        float e = __expf(sc_sh[ti1 * 648 + s] - rowm);
        sc_sh[ti1 * 648 + s] = e;
        sum += e;
    }
    red_sh[tid] = sum;
    __syncthreads();
    if (tid < 16) {
        float tot = 0.f;
#pragma unroll
        for (int l = 0; l < 32; l++) tot += red_sh[tid * 32 + l];
        rden[tid] = 1.f / tot;
    }
    __syncthreads();

    // ---- PV: wave -> (c-tile = (w&3)*16, K-half = w>>2); 10 ks steps ----
    int cw = (wave & 3) * 16, kh = wave >> 2;
    const unsigned short* vb = vT_h + ((size_t)b * 64 + cw + nlo) * TPAD;
    f32x4 cacc = {0.f, 0.f, 0.f, 0.f};
    int ks0 = kh * 10;
#pragma unroll 5
    for (int i = 0; i < 10; ++i) {
        int ks = ks0 + i;
        const float* pr = &sc_sh[nlo * 648 + ks * 32 + quad * 8];
        union { unsigned short u[8]; bf16x8 v; } P;
#pragma unroll
        for (int j = 0; j < 8; ++j) P.u[j] = f32_to_bf16_rne(pr[j]);
        bf16x8 v8 = *(const bf16x8*)(vb + ks * 32 + quad * 8);
        cacc = mfma_bf16(P.v, v8, cacc);
    }
#pragma unroll
    for (int r = 0; r < 4; ++r)
        ctx_sh[kh * 1088 + (cw + nlo) * 17 + quad * 4 + r] = cacc[r] * rden[quad * 4 + r];
    __syncthreads();

    // ---- epilogue (waves 0-3): out = y + wo @ ctx, wave -> o-tile ----
    if (wave < 4) {
        const unsigned short* woh = wo_h + (size_t)(wave * 16 + nlo) * 64 + quad * 8;
        const unsigned short* wol = wo_l + (size_t)(wave * 16 + nlo) * 64 + quad * 8;
        f32x4 oacc = {0.f, 0.f, 0.f, 0.f};
#pragma unroll
        for (int ks = 0; ks < 2; ++ks) {
            union { unsigned short u[8]; bf16x8 v; } Bc;
#pragma unroll
            for (int j = 0; j < 8; ++j) {
                int c = ks * 32 + quad * 8 + j;
                float cv = ctx_sh[c * 17 + nlo] + ctx_sh[1088 + c * 17 + nlo];
                Bc.u[j] = f32_to_bf16_rne(cv);
            }
            bf16x8 ah = *(const bf16x8*)(woh + ks * 32);
            bf16x8 al = *(const bf16x8*)(wol + ks * 32);
            oacc = mfma_bf16(ah, Bc.v, oacc);
            oacc = mfma_bf16(al, Bc.v, oacc);
        }
        int t_g = t0 + nlo;
        if (t_g < TOUT) {
#pragma unroll
            for (int r = 0; r < 4; ++r) {
                int o = wave * 16 + quad * 4 + r;
                size_t off = ((size_t)b * COUT + o) * TOUT + t_g;
                out[off] = y[off] + oacc[r];
            }
        }
    }
}

// ---------------------------------------------------------------------------
extern "C" void kernel_launch(void* const* d_in, const int* in_sizes, int n_in,
                              void* d_out, int out_size, void* d_ws, size_t ws_size,
                              hipStream_t stream) {
    const float* x        = (const float*)d_in[0];
    const float* conv_w   = (const float*)d_in[1];
    const float* conv_b   = (const float*)d_in[2];
    const float* bn_gamma = (const float*)d_in[3];
    const float* bn_beta  = (const float*)d_in[4];
    const float* bn_mean  = (const float*)d_in[5];
    const float* bn_var   = (const float*)d_in[6];
    const float* wq       = (const float*)d_in[7];
    const float* wk       = (const float*)d_in[8];
    const float* wv       = (const float*)d_in[9];
    const float* wo       = (const float*)d_in[10];
    float* out = (float*)d_out;
    float* ws  = (float*)d_ws;

    // ws layout (float offsets)
    unsigned* sgn2        = (unsigned*)ws;                    // 6912 u32
    float* alpha          = ws + 110592;                      // 64
    float* scA            = ws + 110656;                      // 64
    float* scB            = ws + 110720;                      // 64
    float* wT4            = ws + 110848;                      // 3*4096 -> 123136
    unsigned short* wo_h  = (unsigned short*)(ws + 123136);   // 2048 f
    unsigned short* wo_l  = (unsigned short*)(ws + 125184);   // 2048 f -> 127232
    float* yb             = ws + 131072;                      // 5,120,000
    unsigned short* q_h   = (unsigned short*)(ws + 5251072);  // 2,621,440 f
    unsigned short* k_h   = (unsigned short*)(ws + 7872512);  // 2,621,440 f
    unsigned short* vT_h  = (unsigned short*)(ws + 10493952); // ends 13,115,392 f

    hipLaunchKernelGGL(binarize_kernel, dim3(64), dim3(256), 0, stream, conv_w, sgn2, alpha);
    hipLaunchKernelGGL(transpose_w_kernel, dim3(5), dim3(256), 0, stream,
                       wq, wk, wv, wo, conv_b, bn_gamma, bn_beta, bn_mean, bn_var, alpha,
                       wT4, wo_h, wo_l, scA, scB);
    hipLaunchKernelGGL(conv_kernel, dim3(20, 128), dim3(256), 0, stream,
                       x, sgn2, scA, scB, yb);
    hipLaunchKernelGGL(proj_kernel, dim3(10, 128), dim3(256), 0, stream,
                       yb, wT4, wT4 + 4096, wT4 + 8192, q_h, k_h, vT_h);
    hipLaunchKernelGGL(attn_kernel, dim3(40, 128), dim3(512), 0, stream,
                       q_h, k_h, vT_h, yb, wo_h, wo_l, out);
}